// Round 6
// baseline (180.919 us; speedup 1.0000x reference)
//
#include <hip/hip_runtime.h>

#define BB 32
#define SS 512
#define HH 256
#define NBINS 256
#define TMAX 4096
#define ROWS_PER_BLOCK 128   // each block owns 128 consecutive frames of one batch
#define RPW 16               // rows per wave (8 waves * 16 = 128)

// Boundary i of np.linspace(vmin, vmax, 256) computed as NumPy does:
// step = (vmax-vmin)/255 (f64); b[i] = i*step + vmin (f64); b[255] = vmax.
__device__ __forceinline__ double boundary(int i, double vmin, double vmax, double step) {
    if (i == NBINS - 1) return vmax;
    return (double)i * step + vmin;
}

// searchsorted(boundaries, clip(v,vmin,vmax), side='left'), clipped to [0,255]
__device__ __forceinline__ int quantize_bin(float v, float vminf, float vmaxf) {
    v = fminf(fmaxf(v, vminf), vmaxf);
    double vd = (double)v;
    double vmin = (double)vminf, vmax = (double)vmaxf;
    double step = (vmax - vmin) / (double)(NBINS - 1);
    int g = (int)ceil((vd - vmin) / step);
    g = max(0, min(NBINS - 1, g));
    // enforce: smallest g with vd <= b[g]
    while (g > 0 && vd <= boundary(g - 1, vmin, vmax, step)) g--;
    while (g < NBINS - 1 && vd > boundary(g, vmin, vmax, step)) g++;
    return g;
}

// Fused kernel; phases 1-2 proven (R4/R5). Phase 3 rebuilt BRANCHLESS:
// per row r: packed from LDS broadcast, UNCONDITIONAL e/p/q loads (for
// packed=-1 the bit-masked indices j=511/pb=255/eb=255 are in-bounds),
// result multiplied by (packed>=0). No control dependency between rows ->
// the compiler can software-pipeline all 48 loads + 16 stores per wave,
// hiding L2/L3 latency with ILP instead of serializing per run boundary.
__global__ __launch_bounds__(512)
void fused_kernel(const float* __restrict__ enc,
                  const float* __restrict__ pitch,
                  const float* __restrict__ energy,
                  const float* __restrict__ dur,
                  const float* __restrict__ ptab,
                  const float* __restrict__ etab,
                  float* __restrict__ out) {
    __shared__ int cum[SS];
    __shared__ int pb_sh[SS];
    __shared__ int eb_sh[SS];
    __shared__ int pk_sh[ROWS_PER_BLOCK];

    int blk  = blockIdx.x;        // 0..1023
    int b    = blk >> 5;          // 32 blocks per batch
    int seg  = blk & 31;          // 128-row segment within the batch
    int row0b = seg * ROWS_PER_BLOCK;   // batch-local first frame of this block
    int s = threadIdx.x;

    // ---- phase 1: per-token quantize + duration scan (R0/R4-proven) ----
    int tok = b * SS + s;
    pb_sh[s] = quantize_bin(pitch[tok], 50.0f, 400.0f);
    eb_sh[s] = quantize_bin(energy[tok], 0.0f, 1.0f);
    int d = (int)rintf(dur[tok]);   // np.round: half-to-even
    if (d < 1) d = 1;
    cum[s] = d;
    __syncthreads();

    for (int off = 1; off < SS; off <<= 1) {
        int add = (s >= off) ? cum[s - off] : 0;
        __syncthreads();
        cum[s] += add;
        __syncthreads();
    }
    int total = cum[SS - 1];

    // ---- phase 2: packed map for this block's 128 frames (to LDS) ----
    if (s < ROWS_PER_BLOCK) {
        int t = row0b + s;
        int packed;
        if (t >= total) {
            packed = -1;
        } else {
            // searchsorted(cum, t, 'right') = first j with cum[j] > t
            int lo = 0, hi = SS;
            while (lo < hi) {
                int m = (lo + hi) >> 1;
                if (cum[m] <= t) lo = m + 1; else hi = m;
            }
            int j = (lo > SS - 1) ? (SS - 1) : lo;
            packed = j | (pb_sh[j] << 9) | (eb_sh[j] << 17);
        }
        pk_sh[s] = packed;
    }
    __syncthreads();

    // ---- phase 3: branchless pipelined gather + coalesced stores ----
    int wid  = s >> 6;            // 0..7
    int lane = s & 63;
    int rbase = wid * RPW;        // block-local first row of this wave

    size_t grow0 = (size_t)b * TMAX + row0b + rbase;   // global first row
    float4* outv = reinterpret_cast<float4*>(out + grow0 * HH) + lane;
    const size_t enc_b = (size_t)b * SS;

    #pragma unroll
    for (int r = 0; r < RPW; ++r) {
        int packed = pk_sh[rbase + r];        // uniform LDS broadcast
        int j  = packed & 511;                // packed=-1 -> 511 (in-bounds)
        int pb = (packed >> 9) & 255;         // packed=-1 -> 255 (in-bounds)
        int eb = (packed >> 17) & 255;
        float m = (packed >= 0) ? 1.0f : 0.0f;
        const float4 e = reinterpret_cast<const float4*>(enc  + (enc_b + j) * HH)[lane];
        const float4 p = reinterpret_cast<const float4*>(ptab + (size_t)pb * HH)[lane];
        const float4 q = reinterpret_cast<const float4*>(etab + (size_t)eb * HH)[lane];
        float4 val;
        // match reference association: (enc + pt) + et, then mask padded rows
        val.x = ((e.x + p.x) + q.x) * m;
        val.y = ((e.y + p.y) + q.y) * m;
        val.z = ((e.z + p.z) + q.z) * m;
        val.w = ((e.w + p.w) + q.w) * m;
        outv[(size_t)r * (HH / 4)] = val;
    }
}

extern "C" void kernel_launch(void* const* d_in, const int* in_sizes, int n_in,
                              void* d_out, int out_size, void* d_ws, size_t ws_size,
                              hipStream_t stream) {
    const float* enc    = (const float*)d_in[0];  // [B,S,H]
    const float* pitch  = (const float*)d_in[1];  // [B,S]
    const float* energy = (const float*)d_in[2];  // [B,S]
    const float* dur    = (const float*)d_in[3];  // [B,S]
    const float* ptab   = (const float*)d_in[4];  // [256,H]
    const float* etab   = (const float*)d_in[5];  // [256,H]
    float* out = (float*)d_out;                   // [B,TMAX,H]

    int blocks = (BB * TMAX) / ROWS_PER_BLOCK;    // 1024 blocks x 512 threads
    fused_kernel<<<blocks, 512, 0, stream>>>(enc, pitch, energy, dur, ptab, etab, out);
}

// Round 7
// 177.778 us; speedup vs baseline: 1.0177x; 1.0177x over previous
//
#include <hip/hip_runtime.h>

#define BB 32
#define SS 512
#define HH 256
#define NBINS 256
#define TMAX 4096
#define ROWS_PER_BLOCK 128   // each block owns 128 consecutive frames of one batch
#define RPW 16               // rows per wave (8 waves * 16 = 128)

typedef float f4 __attribute__((ext_vector_type(4)));

// Boundary i of np.linspace(vmin, vmax, 256) computed as NumPy does:
// step = (vmax-vmin)/255 (f64); b[i] = i*step + vmin (f64); b[255] = vmax.
__device__ __forceinline__ double boundary(int i, double vmin, double vmax, double step) {
    if (i == NBINS - 1) return vmax;
    return (double)i * step + vmin;
}

// searchsorted(boundaries, clip(v,vmin,vmax), side='left'), clipped to [0,255]
__device__ __forceinline__ int quantize_bin(float v, float vminf, float vmaxf) {
    v = fminf(fmaxf(v, vminf), vmaxf);
    double vd = (double)v;
    double vmin = (double)vminf, vmax = (double)vmaxf;
    double step = (vmax - vmin) / (double)(NBINS - 1);
    int g = (int)ceil((vd - vmin) / step);
    g = max(0, min(NBINS - 1, g));
    // enforce: smallest g with vd <= b[g]
    while (g > 0 && vd <= boundary(g - 1, vmin, vmax, step)) g--;
    while (g < NBINS - 1 && vd > boundary(g, vmin, vmax, step)) g++;
    return g;
}

// R5-proven fused kernel (run-cached branch gather) + NON-TEMPORAL stores:
// the 134 MB output stream is write-once/never-read; nt keeps it from
// write-allocating in the 4 MiB/XCD L2, which R6 proved the gather loads
// are bandwidth-sensitive to. (R1's nt failure was exonerated by R3's
// byte-identical failure with plain stores — the bug was the shfl scan,
// long since replaced by the proven LDS scan.)
__global__ __launch_bounds__(512)
void fused_kernel(const float* __restrict__ enc,
                  const float* __restrict__ pitch,
                  const float* __restrict__ energy,
                  const float* __restrict__ dur,
                  const float* __restrict__ ptab,
                  const float* __restrict__ etab,
                  float* __restrict__ out) {
    __shared__ int cum[SS];
    __shared__ int pb_sh[SS];
    __shared__ int eb_sh[SS];
    __shared__ int pk_sh[ROWS_PER_BLOCK];

    int blk  = blockIdx.x;        // 0..1023
    int b    = blk >> 5;          // 32 blocks per batch
    int seg  = blk & 31;          // 128-row segment within the batch
    int row0b = seg * ROWS_PER_BLOCK;   // batch-local first frame of this block
    int s = threadIdx.x;

    // ---- phase 1: per-token quantize + duration scan (R0/R4-proven) ----
    int tok = b * SS + s;
    pb_sh[s] = quantize_bin(pitch[tok], 50.0f, 400.0f);
    eb_sh[s] = quantize_bin(energy[tok], 0.0f, 1.0f);
    int d = (int)rintf(dur[tok]);   // np.round: half-to-even
    if (d < 1) d = 1;
    cum[s] = d;
    __syncthreads();

    for (int off = 1; off < SS; off <<= 1) {
        int add = (s >= off) ? cum[s - off] : 0;
        __syncthreads();
        cum[s] += add;
        __syncthreads();
    }
    int total = cum[SS - 1];

    // ---- phase 2: packed map for this block's 128 frames (to LDS) ----
    if (s < ROWS_PER_BLOCK) {
        int t = row0b + s;
        int packed;
        if (t >= total) {
            packed = -1;
        } else {
            // searchsorted(cum, t, 'right') = first j with cum[j] > t
            int lo = 0, hi = SS;
            while (lo < hi) {
                int m = (lo + hi) >> 1;
                if (cum[m] <= t) lo = m + 1; else hi = m;
            }
            int j = (lo > SS - 1) ? (SS - 1) : lo;
            packed = j | (pb_sh[j] << 9) | (eb_sh[j] << 17);
        }
        pk_sh[s] = packed;
    }
    __syncthreads();

    // ---- phase 3: run-cached gather (R5-proven) + nt stores ----
    int wid  = s >> 6;            // 0..7
    int lane = s & 63;
    int rbase = wid * RPW;        // block-local first row of this wave

    int my_packed = (lane < RPW) ? pk_sh[rbase + lane] : 0;

    size_t grow0 = (size_t)b * TMAX + row0b + rbase;   // global first row
    int last_packed = -2;
    f4 val = (f4)(0.f);
    float* outp = out + grow0 * HH + lane * 4;

    #pragma unroll
    for (int r = 0; r < RPW; ++r) {
        int packed = __shfl(my_packed, r);
        if (packed != last_packed) {
            if (packed < 0) {
                val = (f4)(0.f);
            } else {
                int j  = packed & 511;
                int pb = (packed >> 9) & 255;
                int eb = (packed >> 17) & 255;
                int tk = b * SS + j;
                const f4 e = reinterpret_cast<const f4*>(enc  + (size_t)tk * HH)[lane];
                const f4 p = reinterpret_cast<const f4*>(ptab + (size_t)pb * HH)[lane];
                const f4 q = reinterpret_cast<const f4*>(etab + (size_t)eb * HH)[lane];
                // match reference association: (enc + pt) + et
                val = (e + p) + q;
            }
            last_packed = packed;
        }
        __builtin_nontemporal_store(val, reinterpret_cast<f4*>(outp + (size_t)r * HH));
    }
}

extern "C" void kernel_launch(void* const* d_in, const int* in_sizes, int n_in,
                              void* d_out, int out_size, void* d_ws, size_t ws_size,
                              hipStream_t stream) {
    const float* enc    = (const float*)d_in[0];  // [B,S,H]
    const float* pitch  = (const float*)d_in[1];  // [B,S]
    const float* energy = (const float*)d_in[2];  // [B,S]
    const float* dur    = (const float*)d_in[3];  // [B,S]
    const float* ptab   = (const float*)d_in[4];  // [256,H]
    const float* etab   = (const float*)d_in[5];  // [256,H]
    float* out = (float*)d_out;                   // [B,TMAX,H]

    int blocks = (BB * TMAX) / ROWS_PER_BLOCK;    // 1024 blocks x 512 threads
    fused_kernel<<<blocks, 512, 0, stream>>>(enc, pitch, energy, dur, ptab, etab, out);
}

// Round 8
// 169.480 us; speedup vs baseline: 1.0675x; 1.0490x over previous
//
#include <hip/hip_runtime.h>

#define BB 32
#define SS 512
#define HH 256
#define NBINS 256
#define TMAX 4096
#define ROWS_PER_BLOCK 128   // each block owns 128 consecutive frames of one batch
#define RPW 16               // rows per wave (8 waves * 16 = 128)

// Boundary i of np.linspace(vmin, vmax, 256) computed as NumPy does:
// step = (vmax-vmin)/255 (f64); b[i] = i*step + vmin (f64); b[255] = vmax.
__device__ __forceinline__ double boundary(int i, double vmin, double vmax, double step) {
    if (i == NBINS - 1) return vmax;
    return (double)i * step + vmin;
}

// searchsorted(boundaries, clip(v,vmin,vmax), side='left'), clipped to [0,255]
__device__ __forceinline__ int quantize_bin(float v, float vminf, float vmaxf) {
    v = fminf(fmaxf(v, vminf), vmaxf);
    double vd = (double)v;
    double vmin = (double)vminf, vmax = (double)vmaxf;
    double step = (vmax - vmin) / (double)(NBINS - 1);
    int g = (int)ceil((vd - vmin) / step);
    g = max(0, min(NBINS - 1, g));
    // enforce: smallest g with vd <= b[g]
    while (g > 0 && vd <= boundary(g - 1, vmin, vmax, step)) g--;
    while (g < NBINS - 1 && vd > boundary(g, vmin, vmax, step)) g++;
    return g;
}

// Best-measured configuration (R5, 168.9 us): fused single kernel.
//  phase 1: 512 threads quantize all tokens of batch b into LDS,
//           Hillis-Steele scan durations into cum[512] (redundant per
//           block, fully parallel prefix).
//  phase 2: threads 0..127 compute packed = j | pb<<9 | eb<<17 (or -1)
//           for this block's 128 frames, into LDS.
//  phase 3: 8 waves x 16 rows, run-cached float4 gather+add (the branch
//           pays: R6's branchless 3x-load variant cost +12 us of L2 BW),
//           plain coalesced 1KB stores (output is L3-resident; nt stores
//           gain nothing — R7).
// 1024 blocks x 512 threads = 4 blocks/CU. Kernel ~12 us vs ~9 us traffic
// floor; measured region is dominated by ~160 us of harness poison fills.
__global__ __launch_bounds__(512)
void fused_kernel(const float* __restrict__ enc,
                  const float* __restrict__ pitch,
                  const float* __restrict__ energy,
                  const float* __restrict__ dur,
                  const float* __restrict__ ptab,
                  const float* __restrict__ etab,
                  float* __restrict__ out) {
    __shared__ int cum[SS];
    __shared__ int pb_sh[SS];
    __shared__ int eb_sh[SS];
    __shared__ int pk_sh[ROWS_PER_BLOCK];

    int blk  = blockIdx.x;        // 0..1023
    int b    = blk >> 5;          // 32 blocks per batch
    int seg  = blk & 31;          // 128-row segment within the batch
    int row0b = seg * ROWS_PER_BLOCK;   // batch-local first frame of this block
    int s = threadIdx.x;

    // ---- phase 1: per-token quantize + duration scan ----
    int tok = b * SS + s;
    pb_sh[s] = quantize_bin(pitch[tok], 50.0f, 400.0f);
    eb_sh[s] = quantize_bin(energy[tok], 0.0f, 1.0f);
    int d = (int)rintf(dur[tok]);   // np.round: half-to-even
    if (d < 1) d = 1;
    cum[s] = d;
    __syncthreads();

    for (int off = 1; off < SS; off <<= 1) {
        int add = (s >= off) ? cum[s - off] : 0;
        __syncthreads();
        cum[s] += add;
        __syncthreads();
    }
    int total = cum[SS - 1];

    // ---- phase 2: packed map for this block's 128 frames (to LDS) ----
    if (s < ROWS_PER_BLOCK) {
        int t = row0b + s;
        int packed;
        if (t >= total) {
            packed = -1;
        } else {
            // searchsorted(cum, t, 'right') = first j with cum[j] > t
            int lo = 0, hi = SS;
            while (lo < hi) {
                int m = (lo + hi) >> 1;
                if (cum[m] <= t) lo = m + 1; else hi = m;
            }
            int j = (lo > SS - 1) ? (SS - 1) : lo;
            packed = j | (pb_sh[j] << 9) | (eb_sh[j] << 17);
        }
        pk_sh[s] = packed;
    }
    __syncthreads();

    // ---- phase 3: run-cached gather + coalesced stores ----
    int wid  = s >> 6;            // 0..7
    int lane = s & 63;
    int rbase = wid * RPW;        // block-local first row of this wave

    int my_packed = (lane < RPW) ? pk_sh[rbase + lane] : 0;

    size_t grow0 = (size_t)b * TMAX + row0b + rbase;   // global first row
    int last_packed = -2;
    float4 val = make_float4(0.f, 0.f, 0.f, 0.f);
    float4* outv = reinterpret_cast<float4*>(out + grow0 * HH) + lane;

    #pragma unroll
    for (int r = 0; r < RPW; ++r) {
        int packed = __shfl(my_packed, r);
        if (packed != last_packed) {
            if (packed < 0) {
                val = make_float4(0.f, 0.f, 0.f, 0.f);
            } else {
                int j  = packed & 511;
                int pb = (packed >> 9) & 255;
                int eb = (packed >> 17) & 255;
                int tk = b * SS + j;
                const float4 e = reinterpret_cast<const float4*>(enc  + (size_t)tk * HH)[lane];
                const float4 p = reinterpret_cast<const float4*>(ptab + (size_t)pb * HH)[lane];
                const float4 q = reinterpret_cast<const float4*>(etab + (size_t)eb * HH)[lane];
                // match reference association: (enc + pt) + et
                val.x = (e.x + p.x) + q.x;
                val.y = (e.y + p.y) + q.y;
                val.z = (e.z + p.z) + q.z;
                val.w = (e.w + p.w) + q.w;
            }
            last_packed = packed;
        }
        outv[(size_t)r * (HH / 4)] = val;
    }
}

extern "C" void kernel_launch(void* const* d_in, const int* in_sizes, int n_in,
                              void* d_out, int out_size, void* d_ws, size_t ws_size,
                              hipStream_t stream) {
    const float* enc    = (const float*)d_in[0];  // [B,S,H]
    const float* pitch  = (const float*)d_in[1];  // [B,S]
    const float* energy = (const float*)d_in[2];  // [B,S]
    const float* dur    = (const float*)d_in[3];  // [B,S]
    const float* ptab   = (const float*)d_in[4];  // [256,H]
    const float* etab   = (const float*)d_in[5];  // [256,H]
    float* out = (float*)d_out;                   // [B,TMAX,H]

    int blocks = (BB * TMAX) / ROWS_PER_BLOCK;    // 1024 blocks x 512 threads
    fused_kernel<<<blocks, 512, 0, stream>>>(enc, pitch, energy, dur, ptab, etab, out);
}